// Round 5
// baseline (1523.122 us; speedup 1.0000x reference)
//
#include <hip/hip_runtime.h>

#define N_NODES 100000
#define E_EDGES 50000
#define NNZ_CNT 1600000
#define C_IN 128
#define H_OUT 256
#define BKT 128                 // edges per bucket
#define NB 391                  // ceil(E_EDGES / BKT)
#define RPB 4096                // records per binning block

typedef __attribute__((ext_vector_type(8))) short short8;   // 8 bf16 = 4 VGPR
typedef __attribute__((ext_vector_type(4))) float f32x4;    // MFMA accumulator

// RNE float->bf16
__device__ __forceinline__ ushort f2b(float f) {
  union { float f; uint u; } v; v.f = f;
  return (ushort)((v.u + 0x7FFFu + ((v.u >> 16) & 1u)) >> 16);
}
__device__ __forceinline__ float b2f(ushort u) {
  union { uint u; float f; } v; v.u = ((uint)u) << 16;
  return v.f;
}
// LDS float atomic add (ds_add_f32 path)
__device__ __forceinline__ void lds_fadd(float* p, float v) {
  __hip_atomic_fetch_add(p, v, __ATOMIC_RELAXED, __HIP_MEMORY_SCOPE_WORKGROUP);
}

// ---------------------------------------------------------------------------
// Kernel 1: y/batch_0 -> out (f32); zero coarse hist; convert x -> bf16.
// ---------------------------------------------------------------------------
__global__ __launch_bounds__(256) void init_kernel(
    const float* __restrict__ x, const int* __restrict__ y,
    const int* __restrict__ batch0, ushort* __restrict__ xb,
    float* __restrict__ out, int* __restrict__ chist, int nconv4) {
  int i = blockIdx.x * 256 + threadIdx.x;
  if (i < nconv4) {
    float4 v = ((const float4*)x)[i];
    ushort4 u;
    u.x = f2b(v.x); u.y = f2b(v.y); u.z = f2b(v.z); u.w = f2b(v.w);
    ((ushort4*)xb)[i] = u;
  }
  if (i < NB) chist[i] = 0;
  if (i < N_NODES) {
    out[i]           = (float)y[i];
    out[N_NODES + i] = (float)batch0[i];
  }
}

// ---------------------------------------------------------------------------
// Kernel 2: coarse histogram (bucket = row>>7) via LDS hist + merged atomics
// ---------------------------------------------------------------------------
__global__ __launch_bounds__(256) void histc_kernel(
    const int* __restrict__ rows, int* __restrict__ chist) {
  __shared__ int h[NB];
  int t = threadIdx.x;
  for (int b = t; b < NB; b += 256) h[b] = 0;
  __syncthreads();
  int i0 = blockIdx.x * RPB;
  for (int k = 0; k < RPB / 256; ++k) {
    int i = i0 + k * 256 + t;
    if (i < NNZ_CNT) atomicAdd(&h[rows[i] >> 7], 1);
  }
  __syncthreads();
  for (int b = t; b < NB; b += 256)
    if (h[b]) atomicAdd(&chist[b], h[b]);
}

// ---------------------------------------------------------------------------
// Kernel 3: exclusive scan of chist[NB] -> boff[NB+1], gtail[NB]
// ---------------------------------------------------------------------------
__global__ __launch_bounds__(512) void scanc_kernel(
    const int* __restrict__ chist, int* __restrict__ boff,
    int* __restrict__ gtail) {
  __shared__ int s[512];
  int t = threadIdx.x;
  int v = (t < NB) ? chist[t] : 0;
  s[t] = v;
  __syncthreads();
  for (int d = 1; d < 512; d <<= 1) {
    int u = (t >= d) ? s[t - d] : 0;
    __syncthreads();
    s[t] += u;
    __syncthreads();
  }
  if (t < NB) {
    int ex = s[t] - v;
    boff[t]  = ex;
    gtail[t] = ex;
  }
  if (t == 0) boff[NB] = NNZ_CNT;
}

// ---------------------------------------------------------------------------
// Kernel 4: bin records into bucket-clustered uint2 buf:
//   buf[pos] = { (row&127)<<17 | col , bits(val) }
// Per-block LDS hist -> one global reservation per (block,bucket) -> LDS ranks.
// ---------------------------------------------------------------------------
__global__ __launch_bounds__(256) void binpass_kernel(
    const int* __restrict__ rows, const int* __restrict__ cols,
    const float* __restrict__ vals, int* __restrict__ gtail,
    uint2* __restrict__ buf) {
  __shared__ int hist[NB], rnk[NB], base[NB];
  int t = threadIdx.x;
  for (int b = t; b < NB; b += 256) { hist[b] = 0; rnk[b] = 0; }
  __syncthreads();
  int i0 = blockIdx.x * RPB;
  for (int k = 0; k < RPB / 256; ++k) {
    int i = i0 + k * 256 + t;
    if (i < NNZ_CNT) atomicAdd(&hist[rows[i] >> 7], 1);
  }
  __syncthreads();
  for (int b = t; b < NB; b += 256) {
    int c = hist[b];
    base[b] = c ? atomicAdd(&gtail[b], c) : 0;
  }
  __syncthreads();
  for (int k = 0; k < RPB / 256; ++k) {
    int i = i0 + k * 256 + t;
    if (i < NNZ_CNT) {
      int r = rows[i];
      int b = r >> 7;
      int pos = base[b] + atomicAdd(&rnk[b], 1);
      buf[pos] = make_uint2(((uint)(r & (BKT - 1)) << 17) | (uint)cols[i],
                            __float_as_uint(vals[i]));
    }
  }
}

// ---------------------------------------------------------------------------
// Kernel 5: per-bucket accumulate. Block (512 thr, 8 waves) owns 128 edges;
// acc[128][128] f32 in LDS (64KB). One wave per record: 2x128B coalesced bf16
// row loads + 2 ds_add_f32 per lane (channel = lane / lane+64: conflict-free).
// Writes x1 as bf16 (packed u32 stores).
// ---------------------------------------------------------------------------
__global__ __launch_bounds__(512) void edge_accum(
    const ushort* __restrict__ xb, const uint2* __restrict__ buf,
    const int* __restrict__ boff, ushort* __restrict__ x1b) {
  __shared__ float acc[BKT * C_IN];   // 64 KB
  __shared__ uint2 meta[512];
  int t = threadIdx.x, wave = t >> 6, lane = t & 63;

  for (int i = t; i < BKT * C_IN / 4; i += 512)
    ((float4*)acc)[i] = make_float4(0.f, 0.f, 0.f, 0.f);

  int b = blockIdx.x;
  int start = boff[b], end = boff[b + 1];
  for (int base0 = start; base0 < end; base0 += 512) {
    int m = min(512, end - base0);
    __syncthreads();               // acc zeroed / previous chunk consumed
    if (t < m) meta[t] = buf[base0 + t];
    __syncthreads();
    int jend = min(wave * 64 + 64, m);
    for (int j = wave * 64; j < jend; ++j) {
      uint2 rec = meta[j];
      float val = __uint_as_float(rec.y);
      uint  rl  = rec.x >> 17;
      uint  col = rec.x & 0x1FFFFu;
      const ushort* xp = xb + (size_t)col * C_IN;
      float v0 = b2f(xp[lane]);
      float v1 = b2f(xp[64 + lane]);
      lds_fadd(&acc[rl * C_IN + lane],      v0 * val);
      lds_fadd(&acc[rl * C_IN + 64 + lane], v1 * val);
    }
  }
  __syncthreads();

  int e0 = b * BKT;
  int nedge = min(BKT, E_EDGES - e0);
  uint* x1u = (uint*)x1b;
  for (int idx = t; idx < nedge * 64; idx += 512) {
    int e = idx >> 6, p = idx & 63;
    uint lo = f2b(acc[e * C_IN + 2 * p]);
    uint hi = f2b(acc[e * C_IN + 2 * p + 1]);
    x1u[(size_t)(e0 + e) * 64 + p] = lo | (hi << 16);
  }
}

// ---------------------------------------------------------------------------
// Kernel 6: pack W (f32 [128,256]) into per-fragment bf16 layout (as round 3)
// ---------------------------------------------------------------------------
__global__ __launch_bounds__(256) void wprep_kernel(
    const float* __restrict__ W0, const float* __restrict__ W1,
    ushort* __restrict__ Wf) {
  int idx = blockIdx.x * 256 + threadIdx.x;  // 0..8191
  if (idx >= 8192) return;
  const float* W = (idx & 4096) ? W1 : W0;
  int slot = idx & 4095;
  int nt = slot >> 8, ks = (slot >> 6) & 3, lane = slot & 63;
  int c  = nt * 16 + (lane & 15);
  int kb = ks * 32 + ((lane >> 4) << 3);
  short8 v;
#pragma unroll
  for (int j = 0; j < 8; ++j) v[j] = (short)f2b(W[(kb + j) * H_OUT + c]);
  ((short8*)Wf)[idx] = v;
}

// ---------------------------------------------------------------------------
// Kernel 7: out = relu(A @ W + b) via MFMA (verified round 3, unchanged)
// ---------------------------------------------------------------------------
__global__ __launch_bounds__(256) void gemm_mfma(
    const ushort* __restrict__ A, const ushort* __restrict__ Wf,
    const float* __restrict__ bias, float* __restrict__ out, int M) {
  int wave = threadIdx.x >> 6;
  int lane = threadIdx.x & 63;
  int wm = wave >> 1, wn = wave & 1;
  int r0 = blockIdx.x * 64 + wm * 32;

  int arow = lane & 15;
  int kgrp = lane >> 4;

  short8 a[2][4];
#pragma unroll
  for (int mt = 0; mt < 2; ++mt) {
    int row = min(r0 + mt * 16 + arow, M - 1);
    const ushort* ap = A + (size_t)row * C_IN + kgrp * 8;
#pragma unroll
    for (int ks = 0; ks < 4; ++ks)
      a[mt][ks] = *(const short8*)(ap + ks * 32);
  }

  f32x4 acc[2][8];
#pragma unroll
  for (int mt = 0; mt < 2; ++mt)
#pragma unroll
    for (int nt = 0; nt < 8; ++nt) acc[mt][nt] = (f32x4){0.f, 0.f, 0.f, 0.f};

#pragma unroll
  for (int nt = 0; nt < 8; ++nt) {
    int gnt = wn * 8 + nt;
    const short8* bp = (const short8*)Wf + (size_t)(gnt * 4) * 64 + lane;
#pragma unroll
    for (int ks = 0; ks < 4; ++ks) {
      short8 bfrag = bp[(size_t)ks * 64];
      acc[0][nt] = __builtin_amdgcn_mfma_f32_16x16x32_bf16(a[0][ks], bfrag, acc[0][nt], 0, 0, 0);
      acc[1][nt] = __builtin_amdgcn_mfma_f32_16x16x32_bf16(a[1][ks], bfrag, acc[1][nt], 0, 0, 0);
    }
  }

  int crow = kgrp * 4;
  int ccol = lane & 15;
#pragma unroll
  for (int mt = 0; mt < 2; ++mt) {
#pragma unroll
    for (int nt = 0; nt < 8; ++nt) {
      int col = wn * 128 + nt * 16 + ccol;
      float bb = bias[col];
#pragma unroll
      for (int reg = 0; reg < 4; ++reg) {
        int row = r0 + mt * 16 + crow + reg;
        if (row < M)
          out[(size_t)row * H_OUT + col] = fmaxf(acc[mt][nt][reg] + bb, 0.f);
      }
    }
  }
}

// ---------------------------------------------------------------------------
extern "C" void kernel_launch(void* const* d_in, const int* in_sizes, int n_in,
                              void* d_out, int out_size, void* d_ws, size_t ws_size,
                              hipStream_t stream) {
  const float* x        = (const float*)d_in[0];
  const int*   inc_rows = (const int*)d_in[1];
  const int*   inc_cols = (const int*)d_in[2];
  const float* inc_vals = (const float*)d_in[3];
  const int*   y        = (const int*)d_in[4];
  const int*   batch0   = (const int*)d_in[5];
  const float* W0       = (const float*)d_in[6];
  const float* b0       = (const float*)d_in[7];
  const float* W1       = (const float*)d_in[8];
  const float* b1       = (const float*)d_in[9];

  float* out = (float*)d_out;

  // ws: xb 25.6MB | x1b 12.8MB | buf(uint2) 12.8MB | Wf 128KB | chist/boff/gtail
  char* ws = (char*)d_ws;
  ushort* xb    = (ushort*)ws;  ws += (size_t)N_NODES * C_IN * 2;
  ushort* x1b   = (ushort*)ws;  ws += (size_t)E_EDGES * C_IN * 2;
  uint2*  buf   = (uint2*)ws;   ws += (size_t)NNZ_CNT * 8;
  ushort* Wf    = (ushort*)ws;  ws += (size_t)8192 * 8 * 2;
  int*    chist = (int*)ws;     ws += (size_t)NB * 4;
  int*    boff  = (int*)ws;     ws += (size_t)(NB + 1) * 4;
  int*    gtail = (int*)ws;

  const int nconv4 = N_NODES * C_IN / 4;  // 3.2M
  const int nbin   = (NNZ_CNT + RPB - 1) / RPB;  // 391

  init_kernel<<<(nconv4 + 255) / 256, 256, 0, stream>>>(x, y, batch0, xb, out,
                                                        chist, nconv4);
  histc_kernel<<<nbin, 256, 0, stream>>>(inc_rows, chist);
  scanc_kernel<<<1, 512, 0, stream>>>(chist, boff, gtail);
  binpass_kernel<<<nbin, 256, 0, stream>>>(inc_rows, inc_cols, inc_vals,
                                           gtail, buf);
  wprep_kernel<<<32, 256, 0, stream>>>(W0, W1, Wf);
  edge_accum<<<NB, 512, 0, stream>>>(xb, buf, boff, x1b);

  float* x0_out = out + 2 * N_NODES;
  float* x1_out = out + 2 * N_NODES + (size_t)N_NODES * H_OUT;

  gemm_mfma<<<(N_NODES + 63) / 64, 256, 0, stream>>>(xb, Wf, b0, x0_out, N_NODES);
  gemm_mfma<<<(E_EDGES + 63) / 64, 256, 0, stream>>>(x1b, Wf + 8 * 4096, b1,
                                                     x1_out, E_EDGES);
}

// Round 6
// 216.290 us; speedup vs baseline: 7.0420x; 7.0420x over previous
//
#include <hip/hip_runtime.h>

#define N_NODES 100000
#define E_EDGES 50000
#define NNZ_CNT 1600000
#define C_IN 128
#define H_OUT 256
#define BKT 128                 // edges per bucket
#define NB 391                  // ceil(E_EDGES / BKT)
#define RPB 4096                // records per binning block

typedef __attribute__((ext_vector_type(8))) short short8;   // 8 bf16 = 4 VGPR
typedef __attribute__((ext_vector_type(4))) float f32x4;    // MFMA accumulator

// RNE float->bf16
__device__ __forceinline__ ushort f2b(float f) {
  union { float f; uint u; } v; v.f = f;
  return (ushort)((v.u + 0x7FFFu + ((v.u >> 16) & 1u)) >> 16);
}
__device__ __forceinline__ float b2f(ushort u) {
  union { uint u; float f; } v; v.u = ((uint)u) << 16;
  return v.f;
}

// ---------------------------------------------------------------------------
// Kernel 1: y/batch_0 -> out (f32); zero coarse hist; convert x -> bf16.
// ---------------------------------------------------------------------------
__global__ __launch_bounds__(256) void init_kernel(
    const float* __restrict__ x, const int* __restrict__ y,
    const int* __restrict__ batch0, ushort* __restrict__ xb,
    float* __restrict__ out, int* __restrict__ chist, int nconv4) {
  int i = blockIdx.x * 256 + threadIdx.x;
  if (i < nconv4) {
    float4 v = ((const float4*)x)[i];
    ushort4 u;
    u.x = f2b(v.x); u.y = f2b(v.y); u.z = f2b(v.z); u.w = f2b(v.w);
    ((ushort4*)xb)[i] = u;
  }
  if (i < NB) chist[i] = 0;
  if (i < N_NODES) {
    out[i]           = (float)y[i];
    out[N_NODES + i] = (float)batch0[i];
  }
}

// ---------------------------------------------------------------------------
// Kernel 2: coarse histogram (bucket = row>>7) via LDS hist + merged atomics
// ---------------------------------------------------------------------------
__global__ __launch_bounds__(256) void histc_kernel(
    const int* __restrict__ rows, int* __restrict__ chist) {
  __shared__ int h[NB];
  int t = threadIdx.x;
  for (int b = t; b < NB; b += 256) h[b] = 0;
  __syncthreads();
  int i0 = blockIdx.x * RPB;
  for (int k = 0; k < RPB / 256; ++k) {
    int i = i0 + k * 256 + t;
    if (i < NNZ_CNT) atomicAdd(&h[rows[i] >> 7], 1);
  }
  __syncthreads();
  for (int b = t; b < NB; b += 256)
    if (h[b]) atomicAdd(&chist[b], h[b]);
}

// ---------------------------------------------------------------------------
// Kernel 3: scan of chist[NB] -> boff[NB+1], gtail[NB]; seed eoff tail.
// ---------------------------------------------------------------------------
__global__ __launch_bounds__(512) void scanc_kernel(
    const int* __restrict__ chist, int* __restrict__ boff,
    int* __restrict__ gtail, int* __restrict__ eoff) {
  __shared__ int s[512];
  int t = threadIdx.x;
  int v = (t < NB) ? chist[t] : 0;
  s[t] = v;
  __syncthreads();
  for (int d = 1; d < 512; d <<= 1) {
    int u = (t >= d) ? s[t - d] : 0;
    __syncthreads();
    s[t] += u;
    __syncthreads();
  }
  if (t < NB) {
    int ex = s[t] - v;
    boff[t]  = ex;
    gtail[t] = ex;
  }
  if (t == 0) { boff[NB] = NNZ_CNT; eoff[NB * BKT] = NNZ_CNT; }
}

// ---------------------------------------------------------------------------
// Kernel 4: bin records bucket-clustered into buf:
//   buf[pos] = { (row&127)<<17 | col , bits(val) }
// Per-block LDS hist -> one global reservation per (block,bucket) -> LDS rank.
// Writes are contiguous runs (~RPB/NB recs) per (block,bucket): L2-friendly.
// ---------------------------------------------------------------------------
__global__ __launch_bounds__(256) void binpass_kernel(
    const int* __restrict__ rows, const int* __restrict__ cols,
    const float* __restrict__ vals, int* __restrict__ gtail,
    uint2* __restrict__ buf) {
  __shared__ int hist[NB], rnk[NB], base[NB];
  int t = threadIdx.x;
  for (int b = t; b < NB; b += 256) { hist[b] = 0; rnk[b] = 0; }
  __syncthreads();
  int i0 = blockIdx.x * RPB;
  for (int k = 0; k < RPB / 256; ++k) {
    int i = i0 + k * 256 + t;
    if (i < NNZ_CNT) atomicAdd(&hist[rows[i] >> 7], 1);
  }
  __syncthreads();
  for (int b = t; b < NB; b += 256) {
    int c = hist[b];
    base[b] = c ? atomicAdd(&gtail[b], c) : 0;
  }
  __syncthreads();
  for (int k = 0; k < RPB / 256; ++k) {
    int i = i0 + k * 256 + t;
    if (i < NNZ_CNT) {
      int r = rows[i];
      int b = r >> 7;
      int pos = base[b] + atomicAdd(&rnk[b], 1);
      buf[pos] = make_uint2(((uint)(r & (BKT - 1)) << 17) | (uint)cols[i],
                            __float_as_uint(vals[i]));
    }
  }
}

// ---------------------------------------------------------------------------
// Kernel 5: fine regroup within each bucket: exact per-edge CSR.
// One block per bucket; all reads/writes within the bucket's contiguous
// region of buf/buf2 (~33KB): L2-local. Emits eoff[e] per edge.
// ---------------------------------------------------------------------------
__global__ __launch_bounds__(256) void finepass_kernel(
    const uint2* __restrict__ buf, const int* __restrict__ boff,
    uint2* __restrict__ buf2, int* __restrict__ eoff) {
  __shared__ int lhist[BKT], lexc[BKT], lrnk[BKT];
  int t = threadIdx.x;
  int b = blockIdx.x;
  if (t < BKT) { lhist[t] = 0; lrnk[t] = 0; }
  __syncthreads();
  int start = boff[b], end = boff[b + 1];
  for (int i = start + t; i < end; i += 256)
    atomicAdd(&lhist[buf[i].x >> 17], 1);
  __syncthreads();
  if (t < BKT) lexc[t] = lhist[t];
  __syncthreads();
  for (int d = 1; d < BKT; d <<= 1) {           // Hillis-Steele inclusive
    int v = (t < BKT && t >= d) ? lexc[t - d] : 0;
    __syncthreads();
    if (t < BKT) lexc[t] += v;
    __syncthreads();
  }
  if (t < BKT) {
    int ex = lexc[t] - lhist[t];                // -> exclusive
    lexc[t] = ex;
    eoff[b * BKT + t] = start + ex;
  }
  __syncthreads();
  for (int i = start + t; i < end; i += 256) {
    uint2 rec = buf[i];
    int rl = rec.x >> 17;
    int r = atomicAdd(&lrnk[rl], 1);
    buf2[start + lexc[rl] + r] = rec;
  }
}

// ---------------------------------------------------------------------------
// Kernel 6: per-edge gather-reduce (proven round-3 shape). Block = 128
// threads = one edge; thread t owns channel t; records staged in LDS.
// ---------------------------------------------------------------------------
__global__ __launch_bounds__(128) void edge_reduce(
    const ushort* __restrict__ xb, const uint2* __restrict__ buf2,
    const int* __restrict__ eoff, ushort* __restrict__ x1b) {
  __shared__ uint2 meta[128];
  int e = blockIdx.x, t = threadIdx.x;
  int start = eoff[e], end = eoff[e + 1];
  float acc = 0.f;
  for (int base = start; base < end; base += 128) {
    int m = min(128, end - base);
    if (t < m) meta[t] = buf2[base + t];
    __syncthreads();
    for (int j = 0; j < m; ++j) {
      uint2 rec = meta[j];
      acc = fmaf(b2f(xb[(size_t)(rec.x & 0x1FFFFu) * C_IN + t]),
                 __uint_as_float(rec.y), acc);
    }
    __syncthreads();
  }
  x1b[(size_t)e * C_IN + t] = f2b(acc);
}

// ---------------------------------------------------------------------------
// Kernel 7: pack W (f32 [128,256]) into per-fragment bf16 layout (verified)
// ---------------------------------------------------------------------------
__global__ __launch_bounds__(256) void wprep_kernel(
    const float* __restrict__ W0, const float* __restrict__ W1,
    ushort* __restrict__ Wf) {
  int idx = blockIdx.x * 256 + threadIdx.x;  // 0..8191
  if (idx >= 8192) return;
  const float* W = (idx & 4096) ? W1 : W0;
  int slot = idx & 4095;
  int nt = slot >> 8, ks = (slot >> 6) & 3, lane = slot & 63;
  int c  = nt * 16 + (lane & 15);
  int kb = ks * 32 + ((lane >> 4) << 3);
  short8 v;
#pragma unroll
  for (int j = 0; j < 8; ++j) v[j] = (short)f2b(W[(kb + j) * H_OUT + c]);
  ((short8*)Wf)[idx] = v;
}

// ---------------------------------------------------------------------------
// Kernel 8: out = relu(A @ W + b) via MFMA (verified round 3, unchanged)
// ---------------------------------------------------------------------------
__global__ __launch_bounds__(256) void gemm_mfma(
    const ushort* __restrict__ A, const ushort* __restrict__ Wf,
    const float* __restrict__ bias, float* __restrict__ out, int M) {
  int wave = threadIdx.x >> 6;
  int lane = threadIdx.x & 63;
  int wm = wave >> 1, wn = wave & 1;
  int r0 = blockIdx.x * 64 + wm * 32;

  int arow = lane & 15;
  int kgrp = lane >> 4;

  short8 a[2][4];
#pragma unroll
  for (int mt = 0; mt < 2; ++mt) {
    int row = min(r0 + mt * 16 + arow, M - 1);
    const ushort* ap = A + (size_t)row * C_IN + kgrp * 8;
#pragma unroll
    for (int ks = 0; ks < 4; ++ks)
      a[mt][ks] = *(const short8*)(ap + ks * 32);
  }

  f32x4 acc[2][8];
#pragma unroll
  for (int mt = 0; mt < 2; ++mt)
#pragma unroll
    for (int nt = 0; nt < 8; ++nt) acc[mt][nt] = (f32x4){0.f, 0.f, 0.f, 0.f};

#pragma unroll
  for (int nt = 0; nt < 8; ++nt) {
    int gnt = wn * 8 + nt;
    const short8* bp = (const short8*)Wf + (size_t)(gnt * 4) * 64 + lane;
#pragma unroll
    for (int ks = 0; ks < 4; ++ks) {
      short8 bfrag = bp[(size_t)ks * 64];
      acc[0][nt] = __builtin_amdgcn_mfma_f32_16x16x32_bf16(a[0][ks], bfrag, acc[0][nt], 0, 0, 0);
      acc[1][nt] = __builtin_amdgcn_mfma_f32_16x16x32_bf16(a[1][ks], bfrag, acc[1][nt], 0, 0, 0);
    }
  }

  int crow = kgrp * 4;
  int ccol = lane & 15;
#pragma unroll
  for (int mt = 0; mt < 2; ++mt) {
#pragma unroll
    for (int nt = 0; nt < 8; ++nt) {
      int col = wn * 128 + nt * 16 + ccol;
      float bb = bias[col];
#pragma unroll
      for (int reg = 0; reg < 4; ++reg) {
        int row = r0 + mt * 16 + crow + reg;
        if (row < M)
          out[(size_t)row * H_OUT + col] = fmaxf(acc[mt][nt][reg] + bb, 0.f);
      }
    }
  }
}

// ---------------------------------------------------------------------------
extern "C" void kernel_launch(void* const* d_in, const int* in_sizes, int n_in,
                              void* d_out, int out_size, void* d_ws, size_t ws_size,
                              hipStream_t stream) {
  const float* x        = (const float*)d_in[0];
  const int*   inc_rows = (const int*)d_in[1];
  const int*   inc_cols = (const int*)d_in[2];
  const float* inc_vals = (const float*)d_in[3];
  const int*   y        = (const int*)d_in[4];
  const int*   batch0   = (const int*)d_in[5];
  const float* W0       = (const float*)d_in[6];
  const float* b0       = (const float*)d_in[7];
  const float* W1       = (const float*)d_in[8];
  const float* b1       = (const float*)d_in[9];

  float* out = (float*)d_out;

  // ws: xb 25.6MB | x1b 12.8MB | buf 12.8MB | buf2 12.8MB | Wf 128KB |
  //     chist/boff/gtail ~5KB | eoff 200KB   (~65MB total)
  char* ws = (char*)d_ws;
  ushort* xb    = (ushort*)ws;  ws += (size_t)N_NODES * C_IN * 2;
  ushort* x1b   = (ushort*)ws;  ws += (size_t)E_EDGES * C_IN * 2;
  uint2*  buf   = (uint2*)ws;   ws += (size_t)NNZ_CNT * 8;
  uint2*  buf2  = (uint2*)ws;   ws += (size_t)NNZ_CNT * 8;
  ushort* Wf    = (ushort*)ws;  ws += (size_t)8192 * 8 * 2;
  int*    chist = (int*)ws;     ws += (size_t)NB * 4;
  int*    boff  = (int*)ws;     ws += (size_t)(NB + 1) * 4;
  int*    gtail = (int*)ws;     ws += (size_t)NB * 4;
  int*    eoff  = (int*)ws;     // NB*BKT+1 ints

  const int nconv4 = N_NODES * C_IN / 4;         // 3.2M
  const int nbin   = (NNZ_CNT + RPB - 1) / RPB;  // 391

  init_kernel<<<(nconv4 + 255) / 256, 256, 0, stream>>>(x, y, batch0, xb, out,
                                                        chist, nconv4);
  histc_kernel<<<nbin, 256, 0, stream>>>(inc_rows, chist);
  scanc_kernel<<<1, 512, 0, stream>>>(chist, boff, gtail, eoff);
  binpass_kernel<<<nbin, 256, 0, stream>>>(inc_rows, inc_cols, inc_vals,
                                           gtail, buf);
  finepass_kernel<<<NB, 256, 0, stream>>>(buf, boff, buf2, eoff);
  wprep_kernel<<<32, 256, 0, stream>>>(W0, W1, Wf);
  edge_reduce<<<E_EDGES, 128, 0, stream>>>(xb, buf2, eoff, x1b);

  float* x0_out = out + 2 * N_NODES;
  float* x1_out = out + 2 * N_NODES + (size_t)N_NODES * H_OUT;

  gemm_mfma<<<(N_NODES + 63) / 64, 256, 0, stream>>>(xb, Wf, b0, x0_out, N_NODES);
  gemm_mfma<<<(E_EDGES + 63) / 64, 256, 0, stream>>>(x1b, Wf + 8 * 4096, b1,
                                                     x1_out, E_EDGES);
}